// Round 4
// baseline (217.184 us; speedup 1.0000x reference)
//
#include <hip/hip_runtime.h>
#include <hip/hip_bf16.h>
#include <stdint.h>

#define NTOK 8192
#define CD 768
#define HD 3072
#define NE 4
#define MAXT 36            // 256-row tiles: worst case 35, +1 slack
#define GCAP (MAXT * 256)  // 9216 grouped (padded) rows

typedef __attribute__((ext_vector_type(8))) __bf16 bf16x8;
typedef __attribute__((ext_vector_type(4))) float f32x4;

__device__ __forceinline__ void gl_lds16(const void* g, void* l) {
    __builtin_amdgcn_global_load_lds(
        (const __attribute__((address_space(1))) uint32_t*)g,
        (__attribute__((address_space(3))) uint32_t*)l, 16, 0, 0);
}

__device__ __forceinline__ unsigned bf16bits(float v) {
    __hip_bfloat16 h = __float2bfloat16(v);
    return (unsigned)*reinterpret_cast<unsigned short*>(&h);
}

// -------- weight convert (both) + metadata init --------
__global__ __launch_bounds__(256) void k_cvtw(
        const float* __restrict__ wfc, const float* __restrict__ wpr,
        __hip_bfloat16* __restrict__ wfcb, __hip_bfloat16* __restrict__ wprb,
        int* counts, int* fill, int* tilee,
        float* sprob, float* zsum, float* hsum, int* tlist) {
    if (blockIdx.x == 0) {
        int t = threadIdx.x;
        if (t < NE) { counts[t] = 0; fill[t] = 0; sprob[t] = 0.f; }
        if (t == NE) { *zsum = 0.f; *hsum = 0.f; }
        for (int i = t; i < MAXT; i += 256) tilee[i] = -1;
        for (int i = t; i < GCAP; i += 256) tlist[i] = -1;
    }
    const int NW = NE * HD * CD;
    const int stride = gridDim.x * 256 * 8;
    for (int i = (blockIdx.x * 256 + threadIdx.x) * 8; i < NW; i += stride) {
        float4 a = *(const float4*)(wfc + i);
        float4 b = *(const float4*)(wfc + i + 4);
        union { __hip_bfloat16 h[8]; uint4 u; } pk;
        pk.h[0] = __float2bfloat16(a.x); pk.h[1] = __float2bfloat16(a.y);
        pk.h[2] = __float2bfloat16(a.z); pk.h[3] = __float2bfloat16(a.w);
        pk.h[4] = __float2bfloat16(b.x); pk.h[5] = __float2bfloat16(b.y);
        pk.h[6] = __float2bfloat16(b.z); pk.h[7] = __float2bfloat16(b.w);
        *(uint4*)(wfcb + i) = pk.u;
    }
    for (int i = (blockIdx.x * 256 + threadIdx.x) * 8; i < NW; i += stride) {
        float4 a = *(const float4*)(wpr + i);
        float4 b = *(const float4*)(wpr + i + 4);
        union { __hip_bfloat16 h[8]; uint4 u; } pk;
        pk.h[0] = __float2bfloat16(a.x); pk.h[1] = __float2bfloat16(a.y);
        pk.h[2] = __float2bfloat16(a.z); pk.h[3] = __float2bfloat16(a.w);
        pk.h[4] = __float2bfloat16(b.x); pk.h[5] = __float2bfloat16(b.y);
        pk.h[6] = __float2bfloat16(b.z); pk.h[7] = __float2bfloat16(b.w);
        *(uint4*)(wprb + i) = pk.u;
    }
}

// -------- router (fp32 logits, block-reduced stats) + x->bf16 convert --------
__global__ __launch_bounds__(256) void k_router(
        const float* __restrict__ x, const float* __restrict__ wr,
        __hip_bfloat16* __restrict__ xb, int* __restrict__ eidx, int* __restrict__ counts,
        float* __restrict__ sprob, float* __restrict__ zsum, float* __restrict__ hsum) {
    int lane = threadIdx.x & 63;
    int wave = threadIdx.x >> 6;
    float4 wv[NE][3];
    #pragma unroll
    for (int e = 0; e < NE; ++e)
        #pragma unroll
        for (int j = 0; j < 3; ++j)
            wv[e][j] = *(const float4*)(wr + e * CD + j * 256 + lane * 4);
    float sp0 = 0.f, sp1 = 0.f, sp2 = 0.f, sp3 = 0.f, zs = 0.f, hs = 0.f;
    int c0 = 0, c1 = 0, c2 = 0, c3 = 0;
    int t0 = blockIdx.x * 32 + wave * 8;
    for (int it = 0; it < 8; ++it) {
        int t = t0 + it;
        const float* xr = x + (size_t)t * CD;
        float a0 = 0.f, a1 = 0.f, a2 = 0.f, a3 = 0.f;
        #pragma unroll
        for (int j = 0; j < 3; ++j) {
            float4 xv = *(const float4*)(xr + j * 256 + lane * 4);
            a0 += xv.x * wv[0][j].x + xv.y * wv[0][j].y + xv.z * wv[0][j].z + xv.w * wv[0][j].w;
            a1 += xv.x * wv[1][j].x + xv.y * wv[1][j].y + xv.z * wv[1][j].z + xv.w * wv[1][j].w;
            a2 += xv.x * wv[2][j].x + xv.y * wv[2][j].y + xv.z * wv[2][j].z + xv.w * wv[2][j].w;
            a3 += xv.x * wv[3][j].x + xv.y * wv[3][j].y + xv.z * wv[3][j].z + xv.w * wv[3][j].w;
        }
        #pragma unroll
        for (int off = 32; off; off >>= 1) {
            a0 += __shfl_xor(a0, off); a1 += __shfl_xor(a1, off);
            a2 += __shfl_xor(a2, off); a3 += __shfl_xor(a3, off);
        }
        if (lane == 0) {
            float l[NE] = {a0, a1, a2, a3};
            int best = 0; float m = l[0];
            #pragma unroll
            for (int e = 1; e < NE; ++e) if (l[e] > m) { m = l[e]; best = e; }
            float p[NE], s = 0.f;
            #pragma unroll
            for (int e = 0; e < NE; ++e) { p[e] = expf(l[e] - m); s += p[e]; }
            float inv = 1.f / s, ent = 0.f;
            #pragma unroll
            for (int e = 0; e < NE; ++e) {
                p[e] *= inv;
                ent -= p[e] * logf(p[e] + 1e-9f);
            }
            sp0 += p[0]; sp1 += p[1]; sp2 += p[2]; sp3 += p[3];
            float lse = m + logf(s);
            zs += lse * lse; hs += ent;
            if (best == 0) c0++; else if (best == 1) c1++; else if (best == 2) c2++; else c3++;
            eidx[t] = best;
        }
    }
    __shared__ float red[4][10];
    if (lane == 0) {
        red[wave][0] = sp0; red[wave][1] = sp1; red[wave][2] = sp2; red[wave][3] = sp3;
        red[wave][4] = zs;  red[wave][5] = hs;
        red[wave][6] = (float)c0; red[wave][7] = (float)c1;
        red[wave][8] = (float)c2; red[wave][9] = (float)c3;
    }
    __syncthreads();
    if (threadIdx.x == 0) {
        float a[10];
        #pragma unroll
        for (int j = 0; j < 10; ++j)
            a[j] = red[0][j] + red[1][j] + red[2][j] + red[3][j];
        atomicAdd(&sprob[0], a[0]); atomicAdd(&sprob[1], a[1]);
        atomicAdd(&sprob[2], a[2]); atomicAdd(&sprob[3], a[3]);
        atomicAdd(zsum, a[4]); atomicAdd(hsum, a[5]);
        #pragma unroll
        for (int e = 0; e < NE; ++e) atomicAdd(&counts[e], (int)(a[6 + e] + 0.5f));
    }
    // fused x -> bf16 (this block's 32 rows)
    const float* xsrc = x + (size_t)blockIdx.x * 32 * CD;
    __hip_bfloat16* xdst = xb + (size_t)blockIdx.x * 32 * CD;
    #pragma unroll
    for (int c = 0; c < 12; ++c) {
        int i = (c * 256 + threadIdx.x) * 8;
        float4 a = *(const float4*)(xsrc + i);
        float4 b = *(const float4*)(xsrc + i + 4);
        union { __hip_bfloat16 h[8]; uint4 u; } pk;
        pk.h[0] = __float2bfloat16(a.x); pk.h[1] = __float2bfloat16(a.y);
        pk.h[2] = __float2bfloat16(a.z); pk.h[3] = __float2bfloat16(a.w);
        pk.h[4] = __float2bfloat16(b.x); pk.h[5] = __float2bfloat16(b.y);
        pk.h[6] = __float2bfloat16(b.z); pk.h[7] = __float2bfloat16(b.w);
        *(uint4*)(xdst + i) = pk.u;
    }
}

// scan (padded bases + tile map) + final scalar outputs (stats ready post-router)
__global__ void k_scan(const int* counts, int* fill, int* tilee,
                       const float* sprob, const float* zsum, const float* hsum,
                       float* out) {
    int base = 0, nt = 0;
    for (int e = 0; e < NE; ++e) {
        fill[e] = base;
        int tiles = (counts[e] + 255) >> 8;
        for (int i = 0; i < tiles; ++i) tilee[nt++] = e;
        base += tiles << 8;
    }
    float aux = 0.f;
    for (int e = 0; e < NE; ++e) {
        float a = counts[e] / (float)NTOK;
        float ex = sprob[e] / (float)NTOK;
        aux += a * ex;
    }
    out[0] = NE * aux;
    out[1] = (*zsum) / (float)NTOK;
    out[2] = ((*hsum) / (float)NTOK) / logf((float)NE);
    for (int e = 0; e < NE; ++e) out[3 + e] = counts[e] / (float)NTOK;
}

// wave-aggregated scatter
__global__ __launch_bounds__(256) void k_scatter(const int* __restrict__ eidx,
                                                 int* __restrict__ fill,
                                                 int* __restrict__ tlist) {
    int t = blockIdx.x * 256 + threadIdx.x;
    int e = eidx[t];
    int lane = threadIdx.x & 63;
    unsigned long long below = (1ull << lane) - 1ull;
    int base = 0;
    #pragma unroll
    for (int ee = 0; ee < NE; ++ee) {
        unsigned long long mm = __ballot(e == ee);
        if (e == ee) {
            int leader = __ffsll((unsigned long long)mm) - 1;
            int cnt = __popcll(mm);
            int b = 0;
            if (lane == leader) b = atomicAdd(&fill[ee], cnt);
            b = __shfl(b, leader);
            base = b + __popcll(mm & below);
        }
    }
    tlist[base] = t;
}

// -------- grouped GEMM, 256x256 tile, 8-wave, m201-style paired-barrier phases --------
// MODE 1: hbuf = relu(Xg @ Wfc^T)^2 (bf16). MODE 2: y += Hg @ Wproj^T (fp32 atomic, split-K)
template<int MODE, int NT>
__global__ __launch_bounds__(512, 2) void k_gemm(
        const __hip_bfloat16* __restrict__ A, const __hip_bfloat16* __restrict__ Bw,
        const int* __restrict__ tilee, const int* __restrict__ tlist,
        void* __restrict__ outp) {
    constexpr int KDIM  = (MODE == 1) ? CD : HD;
    constexpr int NBROW = (MODE == 1) ? HD : CD;
    constexpr int MFR = 8, MH = 4;                 // per-wave 128x64 -> 8 m-frags
    constexpr int APL = 16384;                     // one kh plane: 256r x 32k bf16
    constexpr int BBASE = 4 * APL;                 // A: 2 slots x 2 kh
    __shared__ __align__(16) char lds[8 * APL];    // 128 KiB

    const int rt = blockIdx.y, ct = blockIdx.x;
    const int e = tilee[rt];
    if (e < 0) return;
    const int kbase = (MODE == 2) ? (int)blockIdx.z * (HD / 2) : 0;
    const int tid = threadIdx.x;
    const int scol = ((tid & 3) ^ ((tid >> 3) & 3)) << 3;   // pre-swizzled source chunk

    const __hip_bfloat16 *aptr0, *aptr1;
    if constexpr (MODE == 1) {
        int g0 = tlist[rt * 256 + (tid >> 2)];       if (g0 < 0) g0 = 0;
        int g1 = tlist[rt * 256 + 128 + (tid >> 2)]; if (g1 < 0) g1 = 0;
        aptr0 = A + (size_t)g0 * KDIM + scol;
        aptr1 = A + (size_t)g1 * KDIM + scol;
    } else {
        aptr0 = A + ((size_t)rt * 256 + (tid >> 2)) * KDIM + kbase + scol;
        aptr1 = aptr0 + (size_t)128 * KDIM;
    }
    const __hip_bfloat16* bptr0 = Bw + ((size_t)e * NBROW + ct * 256 + (tid >> 2)) * KDIM + kbase + scol;
    const __hip_bfloat16* bptr1 = bptr0 + (size_t)128 * KDIM;

    auto stageA = [&](int slot, int kh, int kt2) {
        char* dst = lds + (slot * 2 + kh) * APL + tid * 16;
        size_t ko = (size_t)kt2 * 64 + kh * 32;
        gl_lds16(aptr0 + ko, dst);
        gl_lds16(aptr1 + ko, dst + 8192);
    };
    auto stageB = [&](int slot, int kh, int kt2) {
        char* dst = lds + BBASE + (slot * 2 + kh) * APL + tid * 16;
        size_t ko = (size_t)kt2 * 64 + kh * 32;
        gl_lds16(bptr0 + ko, dst);
        gl_lds16(bptr1 + ko, dst + 8192);
    };

    const int wv = tid >> 6, lane = tid & 63;
    const int wm = wv >> 2, wn = wv & 3;           // 2M x 4N
    const int lr = lane & 15, lq = lane >> 4;

    auto lda = [&](int slot, int kh, int f) -> bf16x8 {
        int r = wm * 128 + f * 16 + lr;
        int off = (slot * 2 + kh) * APL + r * 64 + ((lq ^ ((r >> 1) & 3)) << 4);
        return *(const bf16x8*)(lds + off);
    };
    auto ldb = [&](int slot, int kh, int g) -> bf16x8 {
        int r = wn * 64 + g * 16 + lr;
        int off = BBASE + (slot * 2 + kh) * APL + r * 64 + ((lq ^ ((r >> 1) & 3)) << 4);
        return *(const bf16x8*)(lds + off);
    };

    f32x4 acc[MFR][4];
    #pragma unroll
    for (int f = 0; f < MFR; ++f)
        #pragma unroll
        for (int g = 0; g < 4; ++g) acc[f][g] = (f32x4){0.f, 0.f, 0.f, 0.f};

    #define VMW4() asm volatile("s_waitcnt vmcnt(4)" ::: "memory")
    #define VMW0() asm volatile("s_waitcnt vmcnt(0)" ::: "memory")
    #define MIDBAR() do { __builtin_amdgcn_s_barrier(); \
        asm volatile("s_waitcnt lgkmcnt(0)" ::: "memory"); \
        __builtin_amdgcn_sched_barrier(0); } while (0)
    #define ENDBAR() __builtin_amdgcn_s_barrier()
    #define MFMA_HALF(base) do { __builtin_amdgcn_s_setprio(1); \
        _Pragma("unroll") \
        for (int i = 0; i < MH; ++i) \
            _Pragma("unroll") \
            for (int g = 0; g < 4; ++g) \
                acc[(base) + i][g] = __builtin_amdgcn_mfma_f32_16x16x32_bf16(afr[i], bfr[g], acc[(base) + i][g], 0, 0, 0); \
        __builtin_amdgcn_s_setprio(0); } while (0)

    // prologue: stage kt=0 into slot 0; guarantee kh0 planes before P0 reads
    stageA(0, 0, 0); stageB(0, 0, 0); stageA(0, 1, 0); stageB(0, 1, 0);
    VMW4();
    ENDBAR();

    #pragma unroll 2
    for (int kt = 0; kt < NT; ++kt) {
        const int s = kt & 1, ns = s ^ 1;
        const bool pf = (kt + 1 < NT);
        bf16x8 bfr[4], afr[MH];
        // ---- P0: quadrant (mh0, kh0) ----
        #pragma unroll
        for (int g = 0; g < 4; ++g) bfr[g] = ldb(s, 0, g);
        #pragma unroll
        for (int i = 0; i < MH; ++i) afr[i] = lda(s, 0, i);
        if (pf) stageA(ns, 0, kt + 1);
        MIDBAR();
        MFMA_HALF(0);
        ENDBAR();
        // ---- P1: quadrant (mh1, kh0) ----
        #pragma unroll
        for (int i = 0; i < MH; ++i) afr[i] = lda(s, 0, MH + i);
        if (pf) { stageB(ns, 0, kt + 1); VMW4(); } else VMW0();
        MIDBAR();
        MFMA_HALF(MH);
        ENDBAR();
        // ---- P2: quadrant (mh1, kh1) ----
        #pragma unroll
        for (int g = 0; g < 4; ++g) bfr[g] = ldb(s, 1, g);
        #pragma unroll
        for (int i = 0; i < MH; ++i) afr[i] = lda(s, 1, MH + i);
        if (pf) stageA(ns, 1, kt + 1);
        MIDBAR();
        MFMA_HALF(MH);
        ENDBAR();
        // ---- P3: quadrant (mh0, kh1) ----
        #pragma unroll
        for (int i = 0; i < MH; ++i) afr[i] = lda(s, 1, i);
        if (pf) { stageB(ns, 1, kt + 1); VMW4(); }
        MIDBAR();
        MFMA_HALF(0);
        ENDBAR();
    }

    if constexpr (MODE == 1) {
        __hip_bfloat16* hbuf = (__hip_bfloat16*)outp;
        int colb = ct * 256 + wn * 64;
        #pragma unroll
        for (int f = 0; f < MFR; ++f) {
            int row0 = rt * 256 + wm * 128 + f * 16 + lq * 4;
            #pragma unroll
            for (int g = 0; g < 4; ++g) {
                #pragma unroll
                for (int q = 0; q < 4; ++q) {
                    float v = fmaxf(acc[f][g][q], 0.f);
                    v *= v;
                    unsigned b = bf16bits(v);
                    unsigned ob = (unsigned)__shfl_xor((int)b, 1);
                    if (!(lane & 1))
                        *(unsigned*)(hbuf + (size_t)(row0 + q) * HD + colb + g * 16 + (lr & 14)) = b | (ob << 16);
                }
            }
        }
    } else {
        float* y = (float*)outp;
        #pragma unroll
        for (int f = 0; f < MFR; ++f) {
            #pragma unroll
            for (int q = 0; q < 4; ++q) {
                int grow = rt * 256 + wm * 128 + f * 16 + lq * 4 + q;
                int t = tlist[grow];
                if (t >= 0) {
                    float* yp = y + (size_t)t * CD + ct * 256 + wn * 64 + lr;
                    #pragma unroll
                    for (int g = 0; g < 4; ++g) atomicAdd(yp + g * 16, acc[f][g][q]);
                }
            }
        }
    }
    #undef VMW4
    #undef VMW0
    #undef MIDBAR
    #undef ENDBAR
    #undef MFMA_HALF
}

extern "C" void kernel_launch(void* const* d_in, const int* in_sizes, int n_in,
                              void* d_out, int out_size, void* d_ws, size_t ws_size,
                              hipStream_t stream) {
    const float* x   = (const float*)d_in[0];
    const float* wr  = (const float*)d_in[1];
    const float* wfc = (const float*)d_in[2];
    const float* wpr = (const float*)d_in[3];
    float* y = (float*)d_out;

    char* ws = (char*)d_ws;
    int*   eidx   = (int*)ws;                          // 8192 ints
    int*   counts = (int*)(ws + 32768);
    int*   fill   = (int*)(ws + 32800);
    int*   tilee  = (int*)(ws + 32832);                // 36 ints
    float* sprob  = (float*)(ws + 33024);
    float* zsum   = (float*)(ws + 33040);
    float* hsum   = (float*)(ws + 33044);
    int*   tlist  = (int*)(ws + 33280);                // 9216 ints -> ends 70144
    __hip_bfloat16* xb   = (__hip_bfloat16*)(ws + 70656);                 // 12.6 MB
    __hip_bfloat16* wfcb = (__hip_bfloat16*)(ws + 70656 + 12582912);      // 18.9 MB
    __hip_bfloat16* wprb = (__hip_bfloat16*)(ws + 70656 + 12582912 + 18874368);
    __hip_bfloat16* hbuf = (__hip_bfloat16*)(ws + 70656 + 12582912 + 2 * 18874368);
    // total ws use ~102.2 MB

    hipMemsetAsync(y, 0, (size_t)NTOK * CD * sizeof(float), stream);
    k_cvtw<<<2048, 256, 0, stream>>>(wfc, wpr, wfcb, wprb,
                                     counts, fill, tilee, sprob, zsum, hsum, tlist);
    k_router<<<256, 256, 0, stream>>>(x, wr, xb, eidx, counts, sprob, zsum, hsum);
    k_scan<<<1, 1, 0, stream>>>(counts, fill, tilee, sprob, zsum, hsum,
                                y + (size_t)NTOK * CD);
    k_scatter<<<NTOK / 256, 256, 0, stream>>>(eidx, fill, tlist);
    k_gemm<1, 12><<<dim3(HD / 256, MAXT), 512, 0, stream>>>(xb, wfcb, tilee, tlist, hbuf);
    k_gemm<2, 24><<<dim3(CD / 256, MAXT, 2), 512, 0, stream>>>(hbuf, wprb, tilee, tlist, y);
}

// Round 5
// 181.761 us; speedup vs baseline: 1.1949x; 1.1949x over previous
//
#include <hip/hip_runtime.h>
#include <hip/hip_bf16.h>
#include <stdint.h>

#define NTOK 8192
#define CD 768
#define HD 3072
#define NE 4
#define NRT 68             // 128-row tiles: sum_e ceil(n_e/128) <= 64+4
#define GCAP (NRT * 128)   // 8704 grouped (padded) rows

typedef __attribute__((ext_vector_type(8))) __bf16 bf16x8;
typedef __attribute__((ext_vector_type(4))) float f32x4;

__device__ __forceinline__ void gl_lds16(const void* g, void* l) {
    __builtin_amdgcn_global_load_lds(
        (const __attribute__((address_space(1))) uint32_t*)g,
        (__attribute__((address_space(3))) uint32_t*)l, 16, 0, 0);
}

__device__ __forceinline__ unsigned bf16bits(float v) {
    __hip_bfloat16 h = __float2bfloat16(v);
    return (unsigned)*reinterpret_cast<unsigned short*>(&h);
}

__device__ __forceinline__ void cvt8(const float* __restrict__ in, __hip_bfloat16* __restrict__ out, int i) {
    float4 a = *(const float4*)(in + i);
    float4 b = *(const float4*)(in + i + 4);
    union { __hip_bfloat16 h[8]; uint4 u; } pk;
    pk.h[0] = __float2bfloat16(a.x); pk.h[1] = __float2bfloat16(a.y);
    pk.h[2] = __float2bfloat16(a.z); pk.h[3] = __float2bfloat16(a.w);
    pk.h[4] = __float2bfloat16(b.x); pk.h[5] = __float2bfloat16(b.y);
    pk.h[6] = __float2bfloat16(b.z); pk.h[7] = __float2bfloat16(b.w);
    *(uint4*)(out + i) = pk.u;
}

// -------- fused front: blocks 0..255 = router(+x cvt); blocks 256+ = weight cvt --------
__global__ __launch_bounds__(256) void k_front(
        const float* __restrict__ x, const float* __restrict__ wr,
        const float* __restrict__ wfc, const float* __restrict__ wpr,
        __hip_bfloat16* __restrict__ xb, __hip_bfloat16* __restrict__ wfcb,
        __hip_bfloat16* __restrict__ wprb,
        int* __restrict__ eidx, float* __restrict__ pred) {
    if (blockIdx.x >= 256) {
        const int NW = NE * HD * CD;
        const int stride = (gridDim.x - 256) * 256 * 8;
        int i0 = ((blockIdx.x - 256) * 256 + threadIdx.x) * 8;
        for (int i = i0; i < NW; i += stride) cvt8(wfc, wfcb, i);
        for (int i = i0; i < NW; i += stride) cvt8(wpr, wprb, i);
        return;
    }
    int lane = threadIdx.x & 63;
    int wave = threadIdx.x >> 6;
    float4 wv[NE][3];
    #pragma unroll
    for (int e = 0; e < NE; ++e)
        #pragma unroll
        for (int j = 0; j < 3; ++j)
            wv[e][j] = *(const float4*)(wr + e * CD + j * 256 + lane * 4);
    float sp0 = 0.f, sp1 = 0.f, sp2 = 0.f, sp3 = 0.f, zs = 0.f, hs = 0.f;
    int c0 = 0, c1 = 0, c2 = 0, c3 = 0;
    int t0 = blockIdx.x * 32 + wave * 8;
    for (int it = 0; it < 8; ++it) {
        int t = t0 + it;
        const float* xr = x + (size_t)t * CD;
        float a0 = 0.f, a1 = 0.f, a2 = 0.f, a3 = 0.f;
        #pragma unroll
        for (int j = 0; j < 3; ++j) {
            float4 xv = *(const float4*)(xr + j * 256 + lane * 4);
            a0 += xv.x * wv[0][j].x + xv.y * wv[0][j].y + xv.z * wv[0][j].z + xv.w * wv[0][j].w;
            a1 += xv.x * wv[1][j].x + xv.y * wv[1][j].y + xv.z * wv[1][j].z + xv.w * wv[1][j].w;
            a2 += xv.x * wv[2][j].x + xv.y * wv[2][j].y + xv.z * wv[2][j].z + xv.w * wv[2][j].w;
            a3 += xv.x * wv[3][j].x + xv.y * wv[3][j].y + xv.z * wv[3][j].z + xv.w * wv[3][j].w;
        }
        #pragma unroll
        for (int off = 32; off; off >>= 1) {
            a0 += __shfl_xor(a0, off); a1 += __shfl_xor(a1, off);
            a2 += __shfl_xor(a2, off); a3 += __shfl_xor(a3, off);
        }
        if (lane == 0) {
            float l[NE] = {a0, a1, a2, a3};
            int best = 0; float m = l[0];
            #pragma unroll
            for (int e = 1; e < NE; ++e) if (l[e] > m) { m = l[e]; best = e; }
            float p[NE], s = 0.f;
            #pragma unroll
            for (int e = 0; e < NE; ++e) { p[e] = expf(l[e] - m); s += p[e]; }
            float inv = 1.f / s, ent = 0.f;
            #pragma unroll
            for (int e = 0; e < NE; ++e) {
                p[e] *= inv;
                ent -= p[e] * logf(p[e] + 1e-9f);
            }
            sp0 += p[0]; sp1 += p[1]; sp2 += p[2]; sp3 += p[3];
            float lse = m + logf(s);
            zs += lse * lse; hs += ent;
            if (best == 0) c0++; else if (best == 1) c1++; else if (best == 2) c2++; else c3++;
            eidx[t] = best;
        }
    }
    __shared__ float red[4][10];
    if (lane == 0) {
        red[wave][0] = sp0; red[wave][1] = sp1; red[wave][2] = sp2; red[wave][3] = sp3;
        red[wave][4] = zs;  red[wave][5] = hs;
        red[wave][6] = (float)c0; red[wave][7] = (float)c1;
        red[wave][8] = (float)c2; red[wave][9] = (float)c3;
    }
    __syncthreads();
    if (threadIdx.x < 10)
        pred[blockIdx.x * 10 + threadIdx.x] =
            red[0][threadIdx.x] + red[1][threadIdx.x] + red[2][threadIdx.x] + red[3][threadIdx.x];
    // fused x -> bf16 (this block's 32 rows)
    const float* xsrc = x + (size_t)blockIdx.x * 32 * CD;
    __hip_bfloat16* xdst = xb + (size_t)blockIdx.x * 32 * CD;
    #pragma unroll
    for (int c = 0; c < 12; ++c) cvt8(xsrc, xdst, (c * 256 + threadIdx.x) * 8);
}

// -------- reduce partials, build tile map, scalar outputs, init tlist --------
__global__ __launch_bounds__(256) void k_scan(
        const float* __restrict__ pred, int* counts, int* fill, int* tilee,
        int* tlist, float* out) {
    __shared__ float sm[10];
    if (threadIdx.x < 10) {
        float s = 0.f;
        for (int i = 0; i < 256; ++i) s += pred[i * 10 + threadIdx.x];
        sm[threadIdx.x] = s;
    }
    for (int i = threadIdx.x; i < GCAP; i += 256) tlist[i] = -1;
    __syncthreads();
    if (threadIdx.x == 0) {
        int cnt[NE];
        #pragma unroll
        for (int e = 0; e < NE; ++e) cnt[e] = (int)(sm[6 + e] + 0.5f);
        int base = 0, nt = 0;
        for (int e = 0; e < NE; ++e) {
            counts[e] = cnt[e];
            fill[e] = base;
            int tiles = (cnt[e] + 127) >> 7;
            for (int i = 0; i < tiles; ++i) tilee[nt++] = e;
            base += tiles << 7;
        }
        for (int i = nt; i < NRT; ++i) tilee[i] = -1;
        float aux = 0.f;
        for (int e = 0; e < NE; ++e)
            aux += (cnt[e] / (float)NTOK) * (sm[e] / (float)NTOK);
        out[0] = NE * aux;
        out[1] = sm[4] / (float)NTOK;
        out[2] = (sm[5] / (float)NTOK) / logf((float)NE);
        for (int e = 0; e < NE; ++e) out[3 + e] = cnt[e] / (float)NTOK;
    }
}

// wave-aggregated scatter
__global__ __launch_bounds__(256) void k_scatter(const int* __restrict__ eidx,
                                                 int* __restrict__ fill,
                                                 int* __restrict__ tlist) {
    int t = blockIdx.x * 256 + threadIdx.x;
    int e = eidx[t];
    int lane = threadIdx.x & 63;
    unsigned long long below = (1ull << lane) - 1ull;
    int base = 0;
    #pragma unroll
    for (int ee = 0; ee < NE; ++ee) {
        unsigned long long mm = __ballot(e == ee);
        if (e == ee) {
            int leader = __ffsll((unsigned long long)mm) - 1;
            int cnt = __popcll(mm);
            int b = 0;
            if (lane == leader) b = atomicAdd(&fill[ee], cnt);
            b = __shfl(b, leader);
            base = b + __popcll(mm & below);
        }
    }
    tlist[base] = t;
}

// -------- grouped GEMM, m97 structure: 128x128 tile, BK=64, 4 waves, 32KB LDS --------
// MODE 1: hbuf = relu(Xg @ Wfc^T)^2 (bf16). MODE 2: y = Hg @ Wproj^T (f32 scatter)
template<int MODE>
__global__ __launch_bounds__(256) void k_gemm(
        const __hip_bfloat16* __restrict__ A, const __hip_bfloat16* __restrict__ Bw,
        const int* __restrict__ tilee, const int* __restrict__ tlist,
        void* __restrict__ outp) {
    constexpr int KDIM  = (MODE == 1) ? CD : HD;
    constexpr int NBROW = (MODE == 1) ? HD : CD;
    constexpr int NCT = NBROW / 128;
    constexpr int NKT = KDIM / 64;
    constexpr int NWG = NRT * NCT;       // divisible by 8
    constexpr int CPX = NWG / 8;

    // bijective XCD-chunked swizzle: consecutive logical tiles (sharing A-tile) -> same XCD
    int bid = (int)blockIdx.x;
    int logical = (bid & 7) * CPX + (bid >> 3);
    int ct = logical % NCT, rt = logical / NCT;
    const int e = tilee[rt];
    if (e < 0) return;

    __shared__ __align__(16) __hip_bfloat16 As[128 * 64];
    __shared__ __align__(16) __hip_bfloat16 Bs[128 * 64];
    char* lA = (char*)As;
    char* lB = (char*)Bs;
    const int tid = threadIdx.x;
    const int srow = tid >> 3;                     // 0..31
    const int schunk = (tid & 7) ^ (srow & 7);     // both-sides XOR swizzle (rule #21)

    const __hip_bfloat16 *ap[4], *bp[4];
    #pragma unroll
    for (int i = 0; i < 4; ++i) {
        int r = i * 32 + srow;
        if constexpr (MODE == 1) {
            int gt = tlist[rt * 128 + r];
            if (gt < 0) gt = 0;
            ap[i] = A + (size_t)gt * KDIM + schunk * 8;
        } else {
            ap[i] = A + ((size_t)rt * 128 + r) * KDIM + schunk * 8;
        }
        bp[i] = Bw + ((size_t)e * NBROW + ct * 128 + r) * KDIM + schunk * 8;
    }

    const int wv = tid >> 6, lane = tid & 63;
    const int wm = wv >> 1, wn = wv & 1;           // 2x2 waves, 64x64 each
    const int lr = lane & 15, lq = lane >> 4;

    f32x4 acc[4][4];
    #pragma unroll
    for (int m = 0; m < 4; ++m)
        #pragma unroll
        for (int n = 0; n < 4; ++n) acc[m][n] = (f32x4){0.f, 0.f, 0.f, 0.f};

    for (int kt = 0; kt < NKT; ++kt) {
        __syncthreads();
        #pragma unroll
        for (int i = 0; i < 4; ++i) {
            gl_lds16(ap[i] + kt * 64, lA + i * 4096 + tid * 16);
            gl_lds16(bp[i] + kt * 64, lB + i * 4096 + tid * 16);
        }
        __syncthreads();
        #pragma unroll
        for (int kh = 0; kh < 2; ++kh) {
            bf16x8 af[4], bq[4];
            #pragma unroll
            for (int m = 0; m < 4; ++m) {
                int r = wm * 64 + m * 16 + lr;
                int c = (kh * 4 + lq) ^ (r & 7);
                af[m] = *(const bf16x8*)(lA + r * 128 + c * 16);
            }
            #pragma unroll
            for (int n = 0; n < 4; ++n) {
                int r = wn * 64 + n * 16 + lr;
                int c = (kh * 4 + lq) ^ (r & 7);
                bq[n] = *(const bf16x8*)(lB + r * 128 + c * 16);
            }
            #pragma unroll
            for (int m = 0; m < 4; ++m)
                #pragma unroll
                for (int n = 0; n < 4; ++n)
                    acc[m][n] = __builtin_amdgcn_mfma_f32_16x16x32_bf16(af[m], bq[n], acc[m][n], 0, 0, 0);
        }
    }

    if constexpr (MODE == 1) {
        __hip_bfloat16* hbuf = (__hip_bfloat16*)outp;
        int colb = ct * 128 + wn * 64;
        #pragma unroll
        for (int m = 0; m < 4; ++m) {
            int row0 = rt * 128 + wm * 64 + m * 16 + lq * 4;
            #pragma unroll
            for (int n = 0; n < 4; ++n) {
                #pragma unroll
                for (int q = 0; q < 4; ++q) {
                    float v = fmaxf(acc[m][n][q], 0.f);
                    v *= v;
                    unsigned b = bf16bits(v);
                    unsigned ob = (unsigned)__shfl_xor((int)b, 1);
                    if (!(lane & 1))
                        *(unsigned*)(hbuf + (size_t)(row0 + q) * HD + colb + n * 16 + (lr & 14)) = b | (ob << 16);
                }
            }
        }
    } else {
        float* y = (float*)outp;
        #pragma unroll
        for (int m = 0; m < 4; ++m) {
            #pragma unroll
            for (int q = 0; q < 4; ++q) {
                int grow = rt * 128 + wm * 64 + m * 16 + lq * 4 + q;
                int t = tlist[grow];
                if (t >= 0) {
                    float* yp = y + (size_t)t * CD + ct * 128 + wn * 64 + lr;
                    #pragma unroll
                    for (int n = 0; n < 4; ++n) yp[n * 16] = acc[m][n][q];
                }
            }
        }
    }
}

extern "C" void kernel_launch(void* const* d_in, const int* in_sizes, int n_in,
                              void* d_out, int out_size, void* d_ws, size_t ws_size,
                              hipStream_t stream) {
    const float* x   = (const float*)d_in[0];
    const float* wr  = (const float*)d_in[1];
    const float* wfc = (const float*)d_in[2];
    const float* wpr = (const float*)d_in[3];
    float* y = (float*)d_out;

    char* ws = (char*)d_ws;
    int*   eidx   = (int*)ws;                          // 8192 ints
    int*   counts = (int*)(ws + 32768);
    int*   fill   = (int*)(ws + 32800);
    int*   tilee  = (int*)(ws + 32832);                // 68 ints
    float* pred   = (float*)(ws + 33152);              // 256*10 floats -> ends 43392
    int*   tlist  = (int*)(ws + 43520);                // 8704 ints -> ends 78336
    __hip_bfloat16* xb   = (__hip_bfloat16*)(ws + 78848);                 // 12.6 MB
    __hip_bfloat16* wfcb = (__hip_bfloat16*)(ws + 78848 + 12582912);      // 18.9 MB
    __hip_bfloat16* wprb = (__hip_bfloat16*)(ws + 78848 + 12582912 + 18874368);
    __hip_bfloat16* hbuf = (__hip_bfloat16*)(ws + 78848 + 12582912 + 2 * 18874368);
    // total ws use ~104 MB

    k_front<<<2304, 256, 0, stream>>>(x, wr, wfc, wpr, xb, wfcb, wprb, eidx, pred);
    k_scan<<<1, 256, 0, stream>>>(pred, counts, fill, tilee, tlist,
                                  y + (size_t)NTOK * CD);
    k_scatter<<<NTOK / 256, 256, 0, stream>>>(eidx, fill, tlist);
    k_gemm<1><<<NRT * (HD / 128), 256, 0, stream>>>(xb, wfcb, tilee, tlist, hbuf);
    k_gemm<2><<<NRT * (CD / 128), 256, 0, stream>>>(hbuf, wprb, tilee, tlist, y);
}

// Round 6
// 154.143 us; speedup vs baseline: 1.4090x; 1.1792x over previous
//
#include <hip/hip_runtime.h>
#include <hip/hip_bf16.h>
#include <stdint.h>

#define NTOK 8192
#define CD 768
#define HD 3072
#define NE 4
#define NRT 68             // 128-row tiles: sum_e ceil(n_e/128) <= 64+4
#define GCAP (NRT * 128)   // 8704 grouped (padded) rows
#define CVB 512            // wproj-cvt blocks appended to gemm1 grid

typedef __attribute__((ext_vector_type(8))) __bf16 bf16x8;
typedef __attribute__((ext_vector_type(4))) float f32x4;

__device__ __forceinline__ void gl_lds16(const void* g, void* l) {
    __builtin_amdgcn_global_load_lds(
        (const __attribute__((address_space(1))) uint32_t*)g,
        (__attribute__((address_space(3))) uint32_t*)l, 16, 0, 0);
}

__device__ __forceinline__ unsigned bf16bits(float v) {
    __hip_bfloat16 h = __float2bfloat16(v);
    return (unsigned)*reinterpret_cast<unsigned short*>(&h);
}

__device__ __forceinline__ void cvt8(const float* __restrict__ in, __hip_bfloat16* __restrict__ out, int i) {
    float4 a = *(const float4*)(in + i);
    float4 b = *(const float4*)(in + i + 4);
    union { __hip_bfloat16 h[8]; uint4 u; } pk;
    pk.h[0] = __float2bfloat16(a.x); pk.h[1] = __float2bfloat16(a.y);
    pk.h[2] = __float2bfloat16(a.z); pk.h[3] = __float2bfloat16(a.w);
    pk.h[4] = __float2bfloat16(b.x); pk.h[5] = __float2bfloat16(b.y);
    pk.h[6] = __float2bfloat16(b.z); pk.h[7] = __float2bfloat16(b.w);
    *(uint4*)(out + i) = pk.u;
}

// -------- fused front: blocks 0..255 = router(+x cvt); blocks 256+ = wfc cvt --------
__global__ __launch_bounds__(256) void k_front(
        const float* __restrict__ x, const float* __restrict__ wr,
        const float* __restrict__ wfc,
        __hip_bfloat16* __restrict__ xb, __hip_bfloat16* __restrict__ wfcb,
        int* __restrict__ eidx, float* __restrict__ pred) {
    if (blockIdx.x >= 256) {
        const int NW = NE * HD * CD;
        const int stride = (gridDim.x - 256) * 256 * 8;
        int i0 = ((blockIdx.x - 256) * 256 + threadIdx.x) * 8;
        for (int i = i0; i < NW; i += stride) cvt8(wfc, wfcb, i);
        return;
    }
    int lane = threadIdx.x & 63;
    int wave = threadIdx.x >> 6;
    float4 wv[NE][3];
    #pragma unroll
    for (int e = 0; e < NE; ++e)
        #pragma unroll
        for (int j = 0; j < 3; ++j)
            wv[e][j] = *(const float4*)(wr + e * CD + j * 256 + lane * 4);
    float sp0 = 0.f, sp1 = 0.f, sp2 = 0.f, sp3 = 0.f, zs = 0.f, hs = 0.f;
    int c0 = 0, c1 = 0, c2 = 0, c3 = 0;
    int t0 = blockIdx.x * 32 + wave * 8;
    for (int it = 0; it < 8; ++it) {
        int t = t0 + it;
        const float* xr = x + (size_t)t * CD;
        float a0 = 0.f, a1 = 0.f, a2 = 0.f, a3 = 0.f;
        #pragma unroll
        for (int j = 0; j < 3; ++j) {
            float4 xv = *(const float4*)(xr + j * 256 + lane * 4);
            a0 += xv.x * wv[0][j].x + xv.y * wv[0][j].y + xv.z * wv[0][j].z + xv.w * wv[0][j].w;
            a1 += xv.x * wv[1][j].x + xv.y * wv[1][j].y + xv.z * wv[1][j].z + xv.w * wv[1][j].w;
            a2 += xv.x * wv[2][j].x + xv.y * wv[2][j].y + xv.z * wv[2][j].z + xv.w * wv[2][j].w;
            a3 += xv.x * wv[3][j].x + xv.y * wv[3][j].y + xv.z * wv[3][j].z + xv.w * wv[3][j].w;
        }
        #pragma unroll
        for (int off = 32; off; off >>= 1) {
            a0 += __shfl_xor(a0, off); a1 += __shfl_xor(a1, off);
            a2 += __shfl_xor(a2, off); a3 += __shfl_xor(a3, off);
        }
        if (lane == 0) {
            float l[NE] = {a0, a1, a2, a3};
            int best = 0; float m = l[0];
            #pragma unroll
            for (int e = 1; e < NE; ++e) if (l[e] > m) { m = l[e]; best = e; }
            float p[NE], s = 0.f;
            #pragma unroll
            for (int e = 0; e < NE; ++e) { p[e] = expf(l[e] - m); s += p[e]; }
            float inv = 1.f / s, ent = 0.f;
            #pragma unroll
            for (int e = 0; e < NE; ++e) {
                p[e] *= inv;
                ent -= p[e] * logf(p[e] + 1e-9f);
            }
            sp0 += p[0]; sp1 += p[1]; sp2 += p[2]; sp3 += p[3];
            float lse = m + logf(s);
            zs += lse * lse; hs += ent;
            if (best == 0) c0++; else if (best == 1) c1++; else if (best == 2) c2++; else c3++;
            eidx[t] = best;
        }
    }
    __shared__ float red[4][10];
    if (lane == 0) {
        red[wave][0] = sp0; red[wave][1] = sp1; red[wave][2] = sp2; red[wave][3] = sp3;
        red[wave][4] = zs;  red[wave][5] = hs;
        red[wave][6] = (float)c0; red[wave][7] = (float)c1;
        red[wave][8] = (float)c2; red[wave][9] = (float)c3;
    }
    __syncthreads();
    if (threadIdx.x < 10)
        pred[blockIdx.x * 10 + threadIdx.x] =
            red[0][threadIdx.x] + red[1][threadIdx.x] + red[2][threadIdx.x] + red[3][threadIdx.x];
    // fused x -> bf16 (this block's 32 rows)
    const float* xsrc = x + (size_t)blockIdx.x * 32 * CD;
    __hip_bfloat16* xdst = xb + (size_t)blockIdx.x * 32 * CD;
    #pragma unroll
    for (int c = 0; c < 12; ++c) cvt8(xsrc, xdst, (c * 256 + threadIdx.x) * 8);
}

// -------- reduce partials, build tile map, scalar outputs, init tlist --------
__global__ __launch_bounds__(256) void k_scan(
        const float* __restrict__ pred, int* counts, int* fill, int* tilee,
        int* tlist, float* out) {
    __shared__ float sm[10];
    if (threadIdx.x < 10) {
        float s = 0.f;
        for (int i = 0; i < 256; ++i) s += pred[i * 10 + threadIdx.x];
        sm[threadIdx.x] = s;
    }
    for (int i = threadIdx.x; i < GCAP; i += 256) tlist[i] = -1;
    __syncthreads();
    if (threadIdx.x == 0) {
        int cnt[NE];
        #pragma unroll
        for (int e = 0; e < NE; ++e) cnt[e] = (int)(sm[6 + e] + 0.5f);
        int base = 0, nt = 0;
        for (int e = 0; e < NE; ++e) {
            counts[e] = cnt[e];
            fill[e] = base;
            int tiles = (cnt[e] + 127) >> 7;
            for (int i = 0; i < tiles; ++i) tilee[nt++] = e;
            base += tiles << 7;
        }
        for (int i = nt; i < NRT; ++i) tilee[i] = -1;
        float aux = 0.f;
        for (int e = 0; e < NE; ++e)
            aux += (cnt[e] / (float)NTOK) * (sm[e] / (float)NTOK);
        out[0] = NE * aux;
        out[1] = sm[4] / (float)NTOK;
        out[2] = (sm[5] / (float)NTOK) / logf((float)NE);
        for (int e = 0; e < NE; ++e) out[3 + e] = cnt[e] / (float)NTOK;
    }
}

// wave-aggregated scatter
__global__ __launch_bounds__(256) void k_scatter(const int* __restrict__ eidx,
                                                 int* __restrict__ fill,
                                                 int* __restrict__ tlist) {
    int t = blockIdx.x * 256 + threadIdx.x;
    int e = eidx[t];
    int lane = threadIdx.x & 63;
    unsigned long long below = (1ull << lane) - 1ull;
    int base = 0;
    #pragma unroll
    for (int ee = 0; ee < NE; ++ee) {
        unsigned long long mm = __ballot(e == ee);
        if (e == ee) {
            int leader = __ffsll((unsigned long long)mm) - 1;
            int cnt = __popcll(mm);
            int b = 0;
            if (lane == leader) b = atomicAdd(&fill[ee], cnt);
            b = __shfl(b, leader);
            base = b + __popcll(mm & below);
        }
    }
    tlist[base] = t;
}

// -------- grouped GEMM: 128x128 tile, BK=64, 4 waves, DOUBLE-buffered LDS (64KB),
// counted vmcnt(8) so next tile's 8 global_load_lds stay in flight across compute.
// MODE 1: hbuf = relu(Xg @ Wfc^T)^2 (bf16); extra blocks convert wpr -> bf16.
// MODE 2: y = Hg @ Wproj^T (f32 scatter)
template<int MODE>
__global__ __launch_bounds__(256, 2) void k_gemm(
        const __hip_bfloat16* __restrict__ A, const __hip_bfloat16* __restrict__ Bw,
        const int* __restrict__ tilee, const int* __restrict__ tlist,
        void* __restrict__ outp,
        const float* __restrict__ cvsrc, __hip_bfloat16* __restrict__ cvdst) {
    constexpr int KDIM  = (MODE == 1) ? CD : HD;
    constexpr int NBROW = (MODE == 1) ? HD : CD;
    constexpr int NCT = NBROW / 128;
    constexpr int NKT = KDIM / 64;
    constexpr int NWG = NRT * NCT;       // 1632 / 408, both divisible by 8
    constexpr int CPX = NWG / 8;

    int bid = (int)blockIdx.x;
    if constexpr (MODE == 1) {
        if (bid >= NWG) {                // appended wproj-cvt blocks (overlap with GEMM)
            const int NW = NE * HD * CD;
            const int stride = CVB * 256 * 8;
            int i0 = ((bid - NWG) * 256 + threadIdx.x) * 8;
            for (int i = i0; i < NW; i += stride) cvt8(cvsrc, cvdst, i);
            return;
        }
    }
    // bijective XCD-chunked swizzle
    int logical = (bid & 7) * CPX + (bid >> 3);
    int ct = logical % NCT, rt = logical / NCT;
    const int e = tilee[rt];
    if (e < 0) return;

    __shared__ __align__(16) char lds[65536];   // 2 x (A 16KB + B 16KB)
    const int tid = threadIdx.x;
    const int srow = tid >> 3;                   // 0..31
    const int schunk = (tid & 7) ^ (srow & 7);   // both-sides XOR swizzle (rule #21)

    const __hip_bfloat16 *ap[4], *bp[4];
    #pragma unroll
    for (int i = 0; i < 4; ++i) {
        int r = i * 32 + srow;
        if constexpr (MODE == 1) {
            int gt = tlist[rt * 128 + r];
            if (gt < 0) gt = 0;
            ap[i] = A + (size_t)gt * KDIM + schunk * 8;
        } else {
            ap[i] = A + ((size_t)rt * 128 + r) * KDIM + schunk * 8;
        }
        bp[i] = Bw + ((size_t)e * NBROW + ct * 128 + r) * KDIM + schunk * 8;
    }

    auto stage = [&](int b, int kt) {
        char* base = lds + b * 32768 + tid * 16;
        #pragma unroll
        for (int i = 0; i < 4; ++i) {
            gl_lds16(ap[i] + kt * 64, base + i * 4096);
            gl_lds16(bp[i] + kt * 64, base + 16384 + i * 4096);
        }
    };

    const int wv = tid >> 6, lane = tid & 63;
    const int wm = wv >> 1, wn = wv & 1;           // 2x2 waves, 64x64 each
    const int lr = lane & 15, lq = lane >> 4;

    f32x4 acc[4][4];
    #pragma unroll
    for (int m = 0; m < 4; ++m)
        #pragma unroll
        for (int n = 0; n < 4; ++n) acc[m][n] = (f32x4){0.f, 0.f, 0.f, 0.f};

    stage(0, 0);
    for (int kt = 0; kt < NKT; ++kt) {
        const int cb = kt & 1;
        if (kt + 1 < NKT) {
            stage(cb ^ 1, kt + 1);
            asm volatile("s_waitcnt vmcnt(8)" ::: "memory");  // cur tile landed; next in flight
        } else {
            asm volatile("s_waitcnt vmcnt(0)" ::: "memory");
        }
        __builtin_amdgcn_s_barrier();
        __builtin_amdgcn_sched_barrier(0);
        const char* lA = lds + cb * 32768;
        const char* lB = lA + 16384;
        #pragma unroll
        for (int kh = 0; kh < 2; ++kh) {
            bf16x8 af[4], bq[4];
            #pragma unroll
            for (int m = 0; m < 4; ++m) {
                int r = wm * 64 + m * 16 + lr;
                int c = (kh * 4 + lq) ^ (r & 7);
                af[m] = *(const bf16x8*)(lA + r * 128 + c * 16);
            }
            #pragma unroll
            for (int n = 0; n < 4; ++n) {
                int r = wn * 64 + n * 16 + lr;
                int c = (kh * 4 + lq) ^ (r & 7);
                bq[n] = *(const bf16x8*)(lB + r * 128 + c * 16);
            }
            #pragma unroll
            for (int m = 0; m < 4; ++m)
                #pragma unroll
                for (int n = 0; n < 4; ++n)
                    acc[m][n] = __builtin_amdgcn_mfma_f32_16x16x32_bf16(af[m], bq[n], acc[m][n], 0, 0, 0);
        }
        __builtin_amdgcn_s_barrier();          // reads of cb done -> cb may be restaged
        __builtin_amdgcn_sched_barrier(0);
    }

    if constexpr (MODE == 1) {
        __hip_bfloat16* hbuf = (__hip_bfloat16*)outp;
        int colb = ct * 128 + wn * 64;
        #pragma unroll
        for (int m = 0; m < 4; ++m) {
            int row0 = rt * 128 + wm * 64 + m * 16 + lq * 4;
            #pragma unroll
            for (int n = 0; n < 4; ++n) {
                #pragma unroll
                for (int q = 0; q < 4; ++q) {
                    float v = fmaxf(acc[m][n][q], 0.f);
                    v *= v;
                    unsigned b = bf16bits(v);
                    unsigned ob = (unsigned)__shfl_xor((int)b, 1);
                    if (!(lane & 1))
                        *(unsigned*)(hbuf + (size_t)(row0 + q) * HD + colb + n * 16 + (lr & 14)) = b | (ob << 16);
                }
            }
        }
    } else {
        float* y = (float*)outp;
        #pragma unroll
        for (int m = 0; m < 4; ++m) {
            #pragma unroll
            for (int q = 0; q < 4; ++q) {
                int grow = rt * 128 + wm * 64 + m * 16 + lq * 4 + q;
                int t = tlist[grow];
                if (t >= 0) {
                    float* yp = y + (size_t)t * CD + ct * 128 + wn * 64 + lr;
                    #pragma unroll
                    for (int n = 0; n < 4; ++n) yp[n * 16] = acc[m][n][q];
                }
            }
        }
    }
}

extern "C" void kernel_launch(void* const* d_in, const int* in_sizes, int n_in,
                              void* d_out, int out_size, void* d_ws, size_t ws_size,
                              hipStream_t stream) {
    const float* x   = (const float*)d_in[0];
    const float* wr  = (const float*)d_in[1];
    const float* wfc = (const float*)d_in[2];
    const float* wpr = (const float*)d_in[3];
    float* y = (float*)d_out;

    char* ws = (char*)d_ws;
    int*   eidx   = (int*)ws;                          // 8192 ints
    int*   counts = (int*)(ws + 32768);
    int*   fill   = (int*)(ws + 32800);
    int*   tilee  = (int*)(ws + 32832);                // 68 ints
    float* pred   = (float*)(ws + 33152);              // 256*10 floats
    int*   tlist  = (int*)(ws + 43520);                // 8704 ints
    __hip_bfloat16* xb   = (__hip_bfloat16*)(ws + 78848);                 // 12.6 MB
    __hip_bfloat16* wfcb = (__hip_bfloat16*)(ws + 78848 + 12582912);      // 18.9 MB
    __hip_bfloat16* wprb = (__hip_bfloat16*)(ws + 78848 + 12582912 + 18874368);
    __hip_bfloat16* hbuf = (__hip_bfloat16*)(ws + 78848 + 12582912 + 2 * 18874368);
    // total ws use ~104 MB

    k_front<<<256 + 1024, 256, 0, stream>>>(x, wr, wfc, xb, wfcb, eidx, pred);
    k_scan<<<1, 256, 0, stream>>>(pred, counts, fill, tilee, tlist,
                                  y + (size_t)NTOK * CD);
    k_scatter<<<NTOK / 256, 256, 0, stream>>>(eidx, fill, tlist);
    k_gemm<1><<<NRT * (HD / 128) + CVB, 256, 0, stream>>>(xb, wfcb, tilee, tlist, hbuf,
                                                          wpr, wprb);
    k_gemm<2><<<NRT * (CD / 128), 256, 0, stream>>>(hbuf, wprb, tilee, tlist, y,
                                                    nullptr, nullptr);
}